// Round 3
// baseline (175.601 us; speedup 1.0000x reference)
//
#include <hip/hip_runtime.h>

// MetricLoss: x[8192][128] f32 -> (loss_homo, loss_heter) f32.
// homo: exact per-group algebra (2k*sum||xi||^2 - 2||sum xi||^2).
// heter: bf16 MFMA Gram over upper-triangular tiles + hinge epilogue.

#define BROWS 8192
#define DIM   128
#define GRPK  4
#define NBT   128                // 8192/64 block tiles per dim
#define NPART (NBT*NBT)

typedef __bf16 bf16x8 __attribute__((ext_vector_type(8)));
typedef float  f32x4  __attribute__((ext_vector_type(4)));

__device__ __forceinline__ unsigned short f2bf(float f) {
  unsigned int u = __float_as_uint(f);
  u += 0x7fffu + ((u >> 16) & 1u);   // round-to-nearest-even
  return (unsigned short)(u >> 16);
}

__device__ __forceinline__ float wave_reduce(float v) {
#pragma unroll
  for (int off = 32; off > 0; off >>= 1) v += __shfl_xor(v, off);
  return v;
}

// One wave per group of 4 rows: writes bf16 copy, per-row sq norms, homo partial.
__global__ __launch_bounds__(256) void prep_kernel(
    const float* __restrict__ x, unsigned short* __restrict__ xb,
    float* __restrict__ sq, float* __restrict__ homo_sum) {
  const int wave = threadIdx.x >> 6;
  const int lane = threadIdx.x & 63;
  const int g = blockIdx.x * 4 + wave;           // 2048 groups
  float s0 = 0.f, s1 = 0.f, q = 0.f;
#pragma unroll
  for (int r = 0; r < GRPK; ++r) {
    const int row = g * GRPK + r;
    const float v0 = x[row * DIM + lane];
    const float v1 = x[row * DIM + lane + 64];
    xb[row * DIM + lane]      = f2bf(v0);
    xb[row * DIM + lane + 64] = f2bf(v1);
    s0 += v0; s1 += v1;
    float rq = wave_reduce(v0 * v0 + v1 * v1);   // full row norm^2, all lanes
    if (lane == 0) sq[row] = rq;
    q += rq;
  }
  float ss = wave_reduce(s0 * s0 + s1 * s1);     // ||sum of 4 rows||^2
  if (lane == 0) atomicAdd(homo_sum, 8.f * q - 2.f * ss);  // 2k*q - 2*ss, k=4
}

// 64x64 block tile, 4 waves as 2x2 of 32x32 subtiles. Upper triangle only.
__global__ __launch_bounds__(256) void heter_kernel(
    const unsigned short* __restrict__ xb, const float* __restrict__ sq,
    float* __restrict__ partial) {
  const int bi = blockIdx.y, bj = blockIdx.x;
  if (bj < bi) return;                            // lower tri: partial stays 0 (memset)
  const int wave = threadIdx.x >> 6;
  const int lane = threadIdx.x & 63;
  const int wi = wave >> 1, wj = wave & 1;
  const int r0 = bi * 64 + wi * 32;
  const int c0 = bj * 64 + wj * 32;
  const bool diagBlock = (bi == bj);

  float hs = 0.f;
  if (!(diagBlock && wj < wi)) {                  // skip fully-lower subtiles
    const int lr = lane & 15;                     // row-in-16 (A) / col-in-16 (B)
    const int lk = lane >> 4;                     // k-chunk 0..3
    f32x4 acc[2][2];
#pragma unroll
    for (int a = 0; a < 2; ++a)
#pragma unroll
      for (int b = 0; b < 2; ++b) acc[a][b] = (f32x4){0.f, 0.f, 0.f, 0.f};

#pragma unroll
    for (int ks = 0; ks < 4; ++ks) {
      const int k0 = ks * 32 + lk * 8;
      bf16x8 a0 = *(const bf16x8*)(xb + (r0      + lr) * DIM + k0);
      bf16x8 a1 = *(const bf16x8*)(xb + (r0 + 16 + lr) * DIM + k0);
      bf16x8 b0 = *(const bf16x8*)(xb + (c0      + lr) * DIM + k0);
      bf16x8 b1 = *(const bf16x8*)(xb + (c0 + 16 + lr) * DIM + k0);
      acc[0][0] = __builtin_amdgcn_mfma_f32_16x16x32_bf16(a0, b0, acc[0][0], 0, 0, 0);
      acc[0][1] = __builtin_amdgcn_mfma_f32_16x16x32_bf16(a0, b1, acc[0][1], 0, 0, 0);
      acc[1][0] = __builtin_amdgcn_mfma_f32_16x16x32_bf16(a1, b0, acc[1][0], 0, 0, 0);
      acc[1][1] = __builtin_amdgcn_mfma_f32_16x16x32_bf16(a1, b1, acc[1][1], 0, 0, 0);
    }

    const bool needMask = diagBlock && (wi == wj);
#pragma unroll
    for (int fi = 0; fi < 2; ++fi)
#pragma unroll
      for (int fj = 0; fj < 2; ++fj)
#pragma unroll
        for (int r = 0; r < 4; ++r) {
          const int i = r0 + fi * 16 + lk * 4 + r;   // C/D row = (lane>>4)*4 + reg
          const int j = c0 + fj * 16 + lr;           // C/D col = lane&15
          const float d2 = sq[i] + sq[j] - 2.f * acc[fi][fj][r];
          float h = fmaxf(1.f - d2, 0.f);
          if (needMask && !((i >> 2) < (j >> 2))) h = 0.f;
          hs += h;
        }
  }

  hs = wave_reduce(hs);
  __shared__ float red[4];
  if (lane == 0) red[wave] = hs;
  __syncthreads();
  if (threadIdx.x == 0) partial[bi * NBT + bj] = red[0] + red[1] + red[2] + red[3];
}

__global__ __launch_bounds__(256) void finalize_kernel(
    const float* __restrict__ partial, const float* __restrict__ homo_sum,
    float* __restrict__ out) {
  float s = 0.f;
  for (int i = threadIdx.x; i < NPART; i += 256) s += partial[i];
  s = wave_reduce(s);
  __shared__ float red[4];
  const int wave = threadIdx.x >> 6, lane = threadIdx.x & 63;
  if (lane == 0) red[wave] = s;
  __syncthreads();
  if (threadIdx.x == 0) {
    out[0] = homo_sum[0] / 24576.f;               // (B/k)*k*(k-1)
    out[1] = (red[0] + red[1] + red[2] + red[3]) / 33538048.f;  // C(2048,2)*16
  }
}

extern "C" void kernel_launch(void* const* d_in, const int* in_sizes, int n_in,
                              void* d_out, int out_size, void* d_ws, size_t ws_size,
                              hipStream_t stream) {
  const float* x = (const float*)d_in[0];
  float* out = (float*)d_out;
  char* ws = (char*)d_ws;
  // ws layout (bytes): [0]=homo_sum, [256]=partial[16384], [65792]=sq[8192],
  //                    [98560]=xb bf16[8192*128]  (total ~2.2 MB)
  float* homo = (float*)(ws);
  float* partial = (float*)(ws + 256);
  float* sq = (float*)(ws + 256 + 65536);
  unsigned short* xb = (unsigned short*)(ws + 256 + 65536 + 32768);

  hipMemsetAsync(d_ws, 0, 256 + 65536, stream);   // zero homo + partials
  hipLaunchKernelGGL(prep_kernel, dim3(512), dim3(256), 0, stream, x, xb, sq, homo);
  hipLaunchKernelGGL(heter_kernel, dim3(NBT, NBT), dim3(256), 0, stream, xb, sq, partial);
  hipLaunchKernelGGL(finalize_kernel, dim3(1), dim3(256), 0, stream, partial, homo, out);
}

// Round 5
// 116.448 us; speedup vs baseline: 1.5080x; 1.5080x over previous
//
#include <hip/hip_runtime.h>

// MetricLoss: x[8192][128] f32 -> (loss_homo, loss_heter) f32.
// homo: exact per-group f32 algebra, per-block partials (NO single-address atomics).
// heter: bf16 32x32x16 MFMA Gram, 128x128 block tiles, upper triangle, hinge epilogue.

#define DIM   128
#define NBT   64                 // 8192/128 block tiles per dim
#define NPART (NBT*NBT)
#define NPREP 512                // prep blocks (homo partials)

typedef __bf16 bf16x8 __attribute__((ext_vector_type(8)));
typedef float  f32x16 __attribute__((ext_vector_type(16)));

__device__ __forceinline__ unsigned short f2bf(float f) {
  unsigned int u = __float_as_uint(f);
  u += 0x7fffu + ((u >> 16) & 1u);   // round-to-nearest-even
  return (unsigned short)(u >> 16);
}

__device__ __forceinline__ float wave_reduce(float v) {
#pragma unroll
  for (int off = 32; off > 0; off >>= 1) v += __shfl_xor(v, off);
  return v;
}

// One wave per group of 4 rows: bf16 copy, per-row sq norms, per-BLOCK homo partial.
__global__ __launch_bounds__(256) void prep_kernel(
    const float* __restrict__ x, unsigned short* __restrict__ xb,
    float* __restrict__ sq, float* __restrict__ homo_part) {
  const int wave = threadIdx.x >> 6;
  const int lane = threadIdx.x & 63;
  const int g = blockIdx.x * 4 + wave;           // 2048 groups
  float s0 = 0.f, s1 = 0.f, q = 0.f;
#pragma unroll
  for (int r = 0; r < 4; ++r) {
    const int row = g * 4 + r;
    const float v0 = x[row * DIM + lane];
    const float v1 = x[row * DIM + lane + 64];
    xb[row * DIM + lane]      = f2bf(v0);
    xb[row * DIM + lane + 64] = f2bf(v1);
    s0 += v0; s1 += v1;
    float rq = wave_reduce(v0 * v0 + v1 * v1);   // full row norm^2 (all lanes)
    if (lane == 0) sq[row] = rq;
    q += rq;
  }
  float ss = wave_reduce(s0 * s0 + s1 * s1);     // ||sum of 4 rows||^2
  __shared__ float hred[4];
  if (lane == 0) hred[wave] = 8.f * q - 2.f * ss;   // 2k*q - 2*ss, k=4
  __syncthreads();
  if (threadIdx.x == 0)
    homo_part[blockIdx.x] = hred[0] + hred[1] + hred[2] + hred[3];
}

// Hinge epilogue over a wave's 2x2 of 32x32 fragments. DIAG => r0==c0 wave.
template<bool DIAG>
__device__ __forceinline__ float epilogue(const f32x16 (&acc)[2][2],
                                          const float* __restrict__ sq,
                                          int r0, int c0, int lc, int lk,
                                          float cj0, float cj1) {
  float hs = 0.f;
#pragma unroll
  for (int fi = 0; fi < 2; ++fi) {
#pragma unroll
    for (int r = 0; r < 16; ++r) {
      const int io = fi * 32 + (r & 3) + 8 * (r >> 2) + 4 * lk;  // C/D row offset
      const float si = sq[r0 + io];
#pragma unroll
      for (int fj = 0; fj < 2; ++fj) {
        if (DIAG && fi > fj) continue;           // fully-lower fragment
        float h = fmaxf(fmaf(2.f, acc[fi][fj][r], (fj ? cj1 : cj0) - si), 0.f);
        if (DIAG && fi == fj) {
          const int i = r0 + io;
          const int j = c0 + fj * 32 + lc;
          if (!((i >> 2) < (j >> 2))) h = 0.f;   // group mask on diagonal frags
        }
        hs += h;
      }
    }
  }
  return hs;
}

// 128x128 block tile, 4 waves as 2x2 of 64x64 wave tiles, 32x32x16 bf16 MFMA.
__global__ __launch_bounds__(256) void heter_kernel(
    const unsigned short* __restrict__ xb, const float* __restrict__ sq,
    float* __restrict__ partial) {
  const int bi = blockIdx.y, bj = blockIdx.x;
  if (bj < bi) {                                  // lower tri: write 0 (no memset pass)
    if (threadIdx.x == 0) partial[bi * NBT + bj] = 0.f;
    return;
  }
  const int wave = threadIdx.x >> 6;
  const int lane = threadIdx.x & 63;
  const int wi = wave >> 1, wj = wave & 1;
  const int r0 = bi * 128 + wi * 64;
  const int c0 = bj * 128 + wj * 64;
  const int lc = lane & 31;                       // A row / B col within 32
  const int lk = lane >> 5;                       // k-half selector (k0 = lk*8)

  const bool diagBlock = (bi == bj);
  float hs = 0.f;
  if (!(diagBlock && wj < wi)) {                  // skip fully-lower wave tiles
    const unsigned short* pa0 = xb + (r0 + lc) * DIM + lk * 8;
    const unsigned short* pa1 = pa0 + 32 * DIM;
    const unsigned short* pb0 = xb + (c0 + lc) * DIM + lk * 8;
    const unsigned short* pb1 = pb0 + 32 * DIM;

    f32x16 acc[2][2];
#pragma unroll
    for (int a = 0; a < 2; ++a)
#pragma unroll
      for (int b = 0; b < 2; ++b)
#pragma unroll
        for (int t = 0; t < 16; ++t) acc[a][b][t] = 0.f;

#pragma unroll
    for (int ks = 0; ks < 8; ++ks) {              // K=128 in steps of 16
      const int ko = ks * 16;
      bf16x8 a0 = *(const bf16x8*)(pa0 + ko);
      bf16x8 a1 = *(const bf16x8*)(pa1 + ko);
      bf16x8 b0 = *(const bf16x8*)(pb0 + ko);
      bf16x8 b1 = *(const bf16x8*)(pb1 + ko);
      acc[0][0] = __builtin_amdgcn_mfma_f32_32x32x16_bf16(a0, b0, acc[0][0], 0, 0, 0);
      acc[0][1] = __builtin_amdgcn_mfma_f32_32x32x16_bf16(a0, b1, acc[0][1], 0, 0, 0);
      acc[1][0] = __builtin_amdgcn_mfma_f32_32x32x16_bf16(a1, b0, acc[1][0], 0, 0, 0);
      acc[1][1] = __builtin_amdgcn_mfma_f32_32x32x16_bf16(a1, b1, acc[1][1], 0, 0, 0);
    }

    const float cj0 = 1.f - sq[c0 + lc];
    const float cj1 = 1.f - sq[c0 + 32 + lc];
    const bool diagWave = diagBlock && (wi == wj);  // r0 == c0
    hs = diagWave ? epilogue<true>(acc, sq, r0, c0, lc, lk, cj0, cj1)
                  : epilogue<false>(acc, sq, r0, c0, lc, lk, cj0, cj1);
  }

  hs = wave_reduce(hs);
  __shared__ float red[4];
  if (lane == 0) red[wave] = hs;
  __syncthreads();
  if (threadIdx.x == 0) partial[bi * NBT + bj] = red[0] + red[1] + red[2] + red[3];
}

__global__ __launch_bounds__(256) void finalize_kernel(
    const float* __restrict__ partial, const float* __restrict__ homo_part,
    float* __restrict__ out) {
  float s = 0.f, hmo = 0.f;
  for (int i = threadIdx.x; i < NPART; i += 256) s += partial[i];
  for (int i = threadIdx.x; i < NPREP; i += 256) hmo += homo_part[i];
  s = wave_reduce(s);
  hmo = wave_reduce(hmo);
  __shared__ float red[4], hred[4];
  const int wave = threadIdx.x >> 6, lane = threadIdx.x & 63;
  if (lane == 0) { red[wave] = s; hred[wave] = hmo; }
  __syncthreads();
  if (threadIdx.x == 0) {
    out[0] = (hred[0] + hred[1] + hred[2] + hred[3]) / 24576.f;        // (B/k)*k*(k-1)
    out[1] = (red[0] + red[1] + red[2] + red[3]) / 33538048.f;         // C(2048,2)*16
  }
}

extern "C" void kernel_launch(void* const* d_in, const int* in_sizes, int n_in,
                              void* d_out, int out_size, void* d_ws, size_t ws_size,
                              hipStream_t stream) {
  const float* x = (const float*)d_in[0];
  float* out = (float*)d_out;
  char* ws = (char*)d_ws;
  // ws layout (bytes): [0] homo_part[512]  (2 KB)
  //                    [2048] partial[4096] (16 KB)
  //                    [18432] sq[8192] (32 KB)
  //                    [50432] xb bf16[8192*128] (2 MB)
  float* homo_part = (float*)(ws);
  float* partial   = (float*)(ws + 2048);
  float* sq        = (float*)(ws + 2048 + 16384);
  unsigned short* xb = (unsigned short*)(ws + 2048 + 16384 + 32768);

  hipLaunchKernelGGL(prep_kernel, dim3(NPREP), dim3(256), 0, stream, x, xb, sq, homo_part);
  hipLaunchKernelGGL(heter_kernel, dim3(NBT, NBT), dim3(256), 0, stream, xb, sq, partial);
  hipLaunchKernelGGL(finalize_kernel, dim3(1), dim3(256), 0, stream, partial, homo_part, out);
}

// Round 8
// 78.764 us; speedup vs baseline: 2.2295x; 1.4784x over previous
//
#include <hip/hip_runtime.h>

// MetricLoss: x[8192][128] f32 -> (loss_homo, loss_heter) f32.
// homo: exact per-group f32 algebra in prep (measured absmax 0.0).
// heter: LDS-staged bf16 32x32x16 MFMA Gram over flat triangular grid.
// xb is stored PRE-SWIZZLED (slot s of row holds chunk s^(row&15)) so
// global_load_lds stages linearly and ds_read_b128 is conflict-spread (rule #21).

#define DIM   128
#define NBT   64                  // 8192/128 tiles per dim
#define NTRI  2080                // NBT*(NBT+1)/2 upper-tri tiles
#define NPREP 512

typedef __bf16 bf16x8 __attribute__((ext_vector_type(8)));
typedef float  f32x16 __attribute__((ext_vector_type(16)));

__device__ __forceinline__ unsigned short f2bf(float f) {
  unsigned int u = __float_as_uint(f);
  u += 0x7fffu + ((u >> 16) & 1u);   // round-to-nearest-even
  return (unsigned short)(u >> 16);
}

__device__ __forceinline__ float wave_reduce(float v) {
#pragma unroll
  for (int off = 32; off > 0; off >>= 1) v += __shfl_xor(v, off);
  return v;
}

__device__ __forceinline__ void load_lds16(const void* g, void* l) {
  __builtin_amdgcn_global_load_lds(
      (const __attribute__((address_space(1))) void*)g,
      (__attribute__((address_space(3))) void*)l, 16, 0, 0);
}

// One wave per group of 4 rows. Phase A: norms + exact homo partial (lane=dim).
// Phase B: swizzled bf16 copy (lane = r*16+s; slot s gets chunk s^(row&15)).
__global__ __launch_bounds__(256) void prep_kernel(
    const float* __restrict__ x, unsigned short* __restrict__ xb,
    float* __restrict__ sq, float* __restrict__ homo_part) {
  const int wave = threadIdx.x >> 6;
  const int lane = threadIdx.x & 63;
  const int g = blockIdx.x * 4 + wave;           // 2048 groups
  float s0 = 0.f, s1 = 0.f, q = 0.f;
#pragma unroll
  for (int r = 0; r < 4; ++r) {
    const int row = g * 4 + r;
    const float v0 = x[row * DIM + lane];
    const float v1 = x[row * DIM + lane + 64];
    s0 += v0; s1 += v1;
    float rq = wave_reduce(v0 * v0 + v1 * v1);   // full row norm^2 (all lanes)
    if (lane == 0) sq[row] = rq;
    q += rq;
  }
  float ss = wave_reduce(s0 * s0 + s1 * s1);     // ||sum of 4 rows||^2
  __shared__ float hred[4];
  if (lane == 0) hred[wave] = 8.f * q - 2.f * ss;   // 2k*q - 2*ss, k=4

  // Phase B: swizzled vectorized bf16 write (x rows are L1/L2 hot from phase A)
  const int r = lane >> 4, s = lane & 15;
  const int row = g * 4 + r;
  const int c = s ^ (row & 15);                  // source chunk for slot s
  const float4* px = (const float4*)(x + row * DIM + c * 8);
  const float4 u0 = px[0], u1 = px[1];
  unsigned int p0 = (unsigned)f2bf(u0.x) | ((unsigned)f2bf(u0.y) << 16);
  unsigned int p1 = (unsigned)f2bf(u0.z) | ((unsigned)f2bf(u0.w) << 16);
  unsigned int p2 = (unsigned)f2bf(u1.x) | ((unsigned)f2bf(u1.y) << 16);
  unsigned int p3 = (unsigned)f2bf(u1.z) | ((unsigned)f2bf(u1.w) << 16);
  uint4 pk; pk.x = p0; pk.y = p1; pk.z = p2; pk.w = p3;
  *(uint4*)(xb + row * DIM + s * 8) = pk;        // linear 16B store, coalesced

  __syncthreads();
  if (threadIdx.x == 0)
    homo_part[blockIdx.x] = hred[0] + hred[1] + hred[2] + hred[3];
}

// Hinge epilogue over a wave's 2x2 of 32x32 fragments. DIAG => r0==c0 wave.
template<bool DIAG>
__device__ __forceinline__ float epilogue(const f32x16 (&acc)[2][2],
                                          const float* __restrict__ sq,
                                          int r0, int c0, int lc, int lk,
                                          float cj0, float cj1) {
  float hs = 0.f;
#pragma unroll
  for (int fi = 0; fi < 2; ++fi) {
#pragma unroll
    for (int r = 0; r < 16; ++r) {
      const int io = fi * 32 + (r & 3) + 8 * (r >> 2) + 4 * lk;  // C/D row offset
      const float si = sq[r0 + io];
#pragma unroll
      for (int fj = 0; fj < 2; ++fj) {
        if (DIAG && fi > fj) continue;           // fully-lower fragment
        float h = fmaxf(fmaf(2.f, acc[fi][fj][r], (fj ? cj1 : cj0) - si), 0.f);
        if (DIAG && fi == fj) {
          const int i = r0 + io;
          const int j = c0 + fj * 32 + lc;
          if (!((i >> 2) < (j >> 2))) h = 0.f;   // group mask on diagonal frags
        }
        hs += h;
      }
    }
  }
  return hs;
}

// Flat triangular grid (2080 blocks). 128x128 tile staged in LDS; 4 waves as
// 2x2 of 64x64 wave tiles, 32x32x16 bf16 MFMA from LDS.
__global__ __launch_bounds__(256) void heter_kernel(
    const unsigned short* __restrict__ xb, const float* __restrict__ sq,
    float* __restrict__ partial) {
  __shared__ unsigned short ldsA[128 * DIM];     // 32 KB
  __shared__ unsigned short ldsB[128 * DIM];     // 32 KB

  // XCD swizzle (bijective: 2080 = 8*260) then triangular decode.
  const int t = (blockIdx.x & 7) * (NTRI / 8) + (blockIdx.x >> 3);
  int bi = (int)((129.0f - sqrtf(16641.0f - 8.0f * (float)t)) * 0.5f);
  bi = min(max(bi, 0), NBT - 1);
  while ((bi + 1) * NBT - ((bi + 1) * bi) / 2 <= t) ++bi;   // start(bi+1) <= t
  while (bi * NBT - (bi * (bi - 1)) / 2 > t) --bi;          // start(bi)   >  t
  const int bj = bi + (t - (bi * NBT - (bi * (bi - 1)) / 2));

  const int wave = threadIdx.x >> 6;
  const int lane = threadIdx.x & 63;

  // Stage both 128-row panels (xb already swizzled; linear copy).
  const unsigned short* gA = xb + bi * 128 * DIM;
  const unsigned short* gB = xb + bj * 128 * DIM;
#pragma unroll
  for (int i = 0; i < 8; ++i) {
    const int e = (wave * 32 + i * 4) * DIM;     // 4 rows (1 KB) per instr
    load_lds16(gA + e + lane * 8, &ldsA[e]);
    load_lds16(gB + e + lane * 8, &ldsB[e]);
  }
  __syncthreads();                                // drains vmcnt before barrier

  const int wi = wave >> 1, wj = wave & 1;
  const int lc = lane & 31;                       // A/B row within 32
  const int lk = lane >> 5;                       // k-half selector
  const bool diagBlock = (bi == bj);

  float hs = 0.f;
  if (!(diagBlock && wj < wi)) {                  // skip fully-lower wave tiles
    const int ra = (wi * 64 + lc) * DIM;
    const int rb = (wj * 64 + lc) * DIM;
    const int sl = lc & 15;

    f32x16 acc[2][2];
#pragma unroll
    for (int a = 0; a < 2; ++a)
#pragma unroll
      for (int b = 0; b < 2; ++b)
#pragma unroll
        for (int v = 0; v < 16; ++v) acc[a][b][v] = 0.f;

#pragma unroll
    for (int ks = 0; ks < 8; ++ks) {              // K=128 in steps of 16
      const int so = ((ks * 2 + lk) ^ sl) * 8;    // swizzled slot -> chunk ks*2+lk
      bf16x8 a0 = *(const bf16x8*)&ldsA[ra + so];
      bf16x8 a1 = *(const bf16x8*)&ldsA[ra + 32 * DIM + so];
      bf16x8 b0 = *(const bf16x8*)&ldsB[rb + so];
      bf16x8 b1 = *(const bf16x8*)&ldsB[rb + 32 * DIM + so];
      acc[0][0] = __builtin_amdgcn_mfma_f32_32x32x16_bf16(a0, b0, acc[0][0], 0, 0, 0);
      acc[0][1] = __builtin_amdgcn_mfma_f32_32x32x16_bf16(a0, b1, acc[0][1], 0, 0, 0);
      acc[1][0] = __builtin_amdgcn_mfma_f32_32x32x16_bf16(a1, b0, acc[1][0], 0, 0, 0);
      acc[1][1] = __builtin_amdgcn_mfma_f32_32x32x16_bf16(a1, b1, acc[1][1], 0, 0, 0);
    }

    const int r0 = bi * 128 + wi * 64;
    const int c0 = bj * 128 + wj * 64;
    const float cj0 = 1.f - sq[c0 + lc];
    const float cj1 = 1.f - sq[c0 + 32 + lc];
    const bool diagWave = diagBlock && (wi == wj);
    hs = diagWave ? epilogue<true>(acc, sq, r0, c0, lc, lk, cj0, cj1)
                  : epilogue<false>(acc, sq, r0, c0, lc, lk, cj0, cj1);
  }

  hs = wave_reduce(hs);
  __shared__ float red[4];
  if (lane == 0) red[wave] = hs;
  __syncthreads();
  if (threadIdx.x == 0) partial[t] = red[0] + red[1] + red[2] + red[3];
}

__global__ __launch_bounds__(256) void finalize_kernel(
    const float* __restrict__ partial, const float* __restrict__ homo_part,
    float* __restrict__ out) {
  float s = 0.f, hmo = 0.f;
  for (int i = threadIdx.x; i < NTRI; i += 256) s += partial[i];
  for (int i = threadIdx.x; i < NPREP; i += 256) hmo += homo_part[i];
  s = wave_reduce(s);
  hmo = wave_reduce(hmo);
  __shared__ float red[4], hred[4];
  const int wave = threadIdx.x >> 6, lane = threadIdx.x & 63;
  if (lane == 0) { red[wave] = s; hred[wave] = hmo; }
  __syncthreads();
  if (threadIdx.x == 0) {
    out[0] = (hred[0] + hred[1] + hred[2] + hred[3]) / 24576.f;   // (B/k)*k*(k-1)
    out[1] = (red[0] + red[1] + red[2] + red[3]) / 33538048.f;    // C(2048,2)*16
  }
}

extern "C" void kernel_launch(void* const* d_in, const int* in_sizes, int n_in,
                              void* d_out, int out_size, void* d_ws, size_t ws_size,
                              hipStream_t stream) {
  const float* x = (const float*)d_in[0];
  float* out = (float*)d_out;
  char* ws = (char*)d_ws;
  // ws layout (bytes): [0] homo_part[512] (2 KB)
  //                    [2048] partial[2080] (8320 B, padded to 8448)
  //                    [10496] sq[8192] (32 KB)
  //                    [43264] xb bf16[8192*128] swizzled (2 MB)
  float* homo_part   = (float*)(ws);
  float* partial     = (float*)(ws + 2048);
  float* sq          = (float*)(ws + 10496);
  unsigned short* xb = (unsigned short*)(ws + 43264);

  hipLaunchKernelGGL(prep_kernel, dim3(NPREP), dim3(256), 0, stream, x, xb, sq, homo_part);
  hipLaunchKernelGGL(heter_kernel, dim3(NTRI), dim3(256), 0, stream, xb, sq, partial);
  hipLaunchKernelGGL(finalize_kernel, dim3(1), dim3(256), 0, stream, partial, homo_part, out);
}